// Round 2
// baseline (431.099 us; speedup 1.0000x reference)
//
#include <hip/hip_runtime.h>

#define D_  256
#define K_  1024
#define HW_ 1024      // 32*32
#define N_  32768     // 32*HW_

// workspace layout (bytes)
#define WS_BEST    0          // u64[32768]  (memset 0xFF)
#define WS_COUNTS  262144     // f32[1024]
#define WS_EMBSUM  266240     // f32[262144]
#define WS_LOSS    1314816    // f32
#define WS_NSUM    1314820    // f32
#define WS_ENMAX   1314824    // u32 (max ||e||^2 bits)
#define WS_ZERO0   262144     // zero range start
#define WS_ZEROLEN 1052684    // covers counts..enmax
#define WS_NEWCS   1314828    // f32[1024]
#define WS_ENORM   1318924    // f32[1024]
#define WS_ZNORM   1323020    // f32[32768]
#define WS_E16     1454096    // bf16[1024*256] = 512 KiB (16B aligned)
#define WS_TOTAL   1978384

// output offsets (f32 elements): (z_q_st, loss, indices, new_emb, new_cs, new_es)
#define O_ZQ   0
#define O_LOSS 8388608
#define O_IDX  8388609
#define O_EMB  8421377
#define O_NCS  8683521
#define O_NES  8684545

typedef unsigned short u16;
typedef short bf16x8 __attribute__((ext_vector_type(8)));  // 8 bf16 = 4 VGPRs
typedef float f32x4 __attribute__((ext_vector_type(4)));

// round-to-nearest-even f32 -> bf16 (data has no NaN)
__device__ __forceinline__ unsigned bf16rne(float x) {
  unsigned u = __float_as_uint(x);
  return (u + 0x7FFFu + ((u >> 16) & 1u)) >> 16;
}

// numpy pairwise_sum of 256 squares: two 128-halves, 8 accumulators,
// combine ((r0+r1)+(r2+r3))+((r4+r5)+(r6+r7)). __f*_rn blocks FMA contraction.
__device__ __forceinline__ float pw256_sq(const float* __restrict__ p, int stride) {
  float tot0 = 0.f, tot1 = 0.f;
#pragma unroll
  for (int h = 0; h < 2; ++h) {
    const float* q = p + h * 128 * stride;
    float r[8];
#pragma unroll
    for (int j = 0; j < 8; ++j) { float x = q[j * stride]; r[j] = __fmul_rn(x, x); }
    for (int i = 8; i < 128; i += 8)
#pragma unroll
      for (int j = 0; j < 8; ++j) {
        float x = q[(i + j) * stride];
        r[j] = __fadd_rn(r[j], __fmul_rn(x, x));
      }
    float s = __fadd_rn(__fadd_rn(__fadd_rn(r[0], r[1]), __fadd_rn(r[2], r[3])),
                        __fadd_rn(__fadd_rn(r[4], r[5]), __fadd_rn(r[6], r[7])));
    if (h == 0) tot0 = s; else tot1 = s;
  }
  return __fadd_rn(tot0, tot1);
}

// ---------------- ||z_n||^2, ||e_k||^2 (np order), en_max, E->bf16 ----------------
__global__ void vq_norms_v8(const float* __restrict__ z, const float* __restrict__ E,
                            float* __restrict__ znorm, float* __restrict__ enorm,
                            u16* __restrict__ E16, unsigned* __restrict__ enmax) {
  int t = blockIdx.x * 128 + threadIdx.x;        // 264 x 128 = 33792
  if (t < N_) {
    const float* p = z + (t >> 10) * (D_ * HW_) + (t & 1023);  // stride HW_ over d
    znorm[t] = pw256_sq(p, HW_);
  } else if (t < N_ + K_) {
    int k = t - N_;
    float v = pw256_sq(E + k * D_, 1);
    enorm[k] = v;
    atomicMax(enmax, __float_as_uint(v));        // v > 0 -> bit-monotone
  }
  // E -> bf16, element-parallel grid-stride, coalesced pair loads/stores
  unsigned* E16w = (unsigned*)E16;
  int gsz = gridDim.x * 128;
  for (int wd = t; wd < (K_ * D_ / 2); wd += gsz) {
    float2 x = *(const float2*)(E + 2 * wd);
    E16w[wd] = bf16rne(x.x) | (bf16rne(x.y) << 16);
  }
}

// Exact reference-numerics distance for one (token, code): sequential fp32 FMA
// chain over d=0..255 (byte-identical to the v9/reference path), then
// fl(fl(zn - 2a) + en). Key = (score_bits<<32)|code -> device-scope atomicMin
// merges across the two code-half blocks; lowest code wins ties (np argmin).
__device__ __forceinline__ void exact_update(
    const float* __restrict__ zb, const float* __restrict__ E,
    int t, int c, const float* __restrict__ zn_s, const float* __restrict__ en_s,
    unsigned long long* __restrict__ best) {
  const float* zp = zb + t;             // stride HW_ over d (original f32 z)
  const float* ep = E + c * D_;
  float a = 0.f;
  for (int d0 = 0; d0 < 256; d0 += 8) {
    float zr[8], er[8];
#pragma unroll
    for (int j = 0; j < 8; ++j) { zr[j] = zp[(d0 + j) * HW_]; er[j] = ep[d0 + j]; }
#pragma unroll
    for (int j = 0; j < 8; ++j) a = __fmaf_rn(zr[j], er[j], a);
  }
  float s = __fadd_rn(__fsub_rn(zn_s[t], __fmul_rn(2.0f, a)), en_s[c & 511]);
  // s ~ 200..330 > 0 -> float bits monotone
  unsigned long long key = ((unsigned long long)__float_as_uint(s) << 32) | (unsigned)c;
  atomicMin(&best[t], key);
}

// VALU-speed 16-lane min via DPP (quad_perm ^1, ^2, row_half_mirror, row_mirror)
template <int CTRL>
__device__ __forceinline__ float dppmin(float v) {
  int p = __builtin_amdgcn_update_dpp(0, __float_as_int(v), CTRL, 0xF, 0xF, true);
  return fminf(v, __int_as_float(p));
}

#define TCAP 192   // per-wave trigger-list capacity (expected ~100-180 used)

// ---------------- MFMA distance + argmin with exact verification ----------------
// 1024 blocks x 256 thr, 4 blocks/CU (one full round). Block = 64 tokens x 512
// codes (blockIdx&1 = code half). Wave owns 128 codes in 2 chunks of 64.
// bf16 MFMA approx scores ph = en - 2*(z.e); block-local running min per token
// (LDS atomicMin on ph+4 bits); any ph within margin M of runmin is exactly
// recomputed into the GLOBAL best[] key (merged across halves by atomicMin).
// M = 2^-4*sqrt(zn*en_max)+2e-4 = 2x the worst-case two-sided bf16 error bound,
// so the reference argmin always triggers in its own half-block.
__global__ __launch_bounds__(256, 4) void vq_dist_mfma2(
    const float* __restrict__ z, const float* __restrict__ E,
    const u16* __restrict__ E16,
    const float* __restrict__ znorm, const float* __restrict__ enorm,
    const unsigned* __restrict__ enmax,
    unsigned long long* __restrict__ best_g) {
  // z tile as bf16 in [kb=d>>3][tok][8d] subtiles: frag ds_read_b128 is
  // conflict-free (16 lanes -> 16 consecutive 16B slots per quarter-wave).
  __shared__ __align__(16) u16 zt[32 * 64 * 8];          // 32 KiB
  __shared__ float en_s[512];                             // this half's norms
  __shared__ float zn_s[64];
  __shared__ float mg_s[64];
  __shared__ unsigned rmin_s[64];                         // bits of (min ph)+4.0
  __shared__ unsigned tcount[4];
  __shared__ unsigned tlist[4][TCAP];                     // 3 KiB

  const int tid = threadIdx.x;
  const int tile = blockIdx.x >> 1;          // 0..511 (token tile)
  const int half = blockIdx.x & 1;           // code half
  const int bimg = tile >> 4;
  const int hw0 = (tile & 15) << 6;
  const float* zb = z + bimg * (D_ * HW_) + hw0;
  unsigned long long* best = best_g + bimg * HW_ + hw0;

  if (tid < 64) {
    float zn = znorm[bimg * HW_ + hw0 + tid];
    zn_s[tid] = zn;
    float em = __uint_as_float(*enmax);
    mg_s[tid] = 0.0625f * sqrtf(zn * em) + 2e-4f;   // margin M (proven safe)
    rmin_s[tid] = 0xFFFFFFFFu;                       // own-chunk min lands before use
  }
  if (tid < 4) tcount[tid] = 0;
  for (int i = tid; i < 512; i += 256) en_s[i] = enorm[half * 512 + i];

  // stage z tile -> bf16 LDS. thread: tok = tid&63, kb = (tid>>6)*8 + r.
  // global: 64 lanes read 64 consecutive floats per instr (256B coalesced).
  {
    const int tok = tid & 63;
    const int kbase = (tid >> 6) * 8;
    for (int r = 0; r < 8; ++r) {
      int kb = kbase + r;
      unsigned pk[4];
#pragma unroll
      for (int j = 0; j < 4; ++j) {
        float x0 = zb[(kb * 8 + 2 * j) * HW_ + tok];
        float x1 = zb[(kb * 8 + 2 * j + 1) * HW_ + tok];
        pk[j] = bf16rne(x0) | (bf16rne(x1) << 16);
      }
      uint4 wv; wv.x = pk[0]; wv.y = pk[1]; wv.z = pk[2]; wv.w = pk[3];
      *(uint4*)(zt + kb * 512 + tok * 8) = wv;       // 16B, conflict-free
    }
  }
  __syncthreads();

  const int lane = tid & 63;
  const int w = tid >> 6;
  const int l15 = lane & 15, g = lane >> 4;
  // B-frag base: row = code (l15), k-slice col = kk*32 + g*8
  const u16* Eb = E16 + (unsigned)(half * 512 + w * 128 + l15) * D_ + g * 8;

  // 16 steps = 2 chunks x 8 kk, fully unrolled; ef register ping-pong: loads
  // for step s+1 issue before step s's 16 MFMAs (~L2 latency hidden).
  bf16x8 efA[4], efB[4];
#pragma unroll
  for (int n = 0; n < 4; ++n)
    efA[n] = *(const bf16x8*)(Eb + n * 16 * D_);          // s=0: ch=0,kk=0

  f32x4 acc[4][4];
#pragma unroll
  for (int s = 0; s < 16; ++s) {
    const int ch = s >> 3, kk = s & 7;
    if (kk == 0) {
      f32x4 z4 = {0.f, 0.f, 0.f, 0.f};
#pragma unroll
      for (int m = 0; m < 4; ++m)
#pragma unroll
        for (int n = 0; n < 4; ++n) acc[m][n] = z4;
    }
    if (s < 15) {
      const int sn = s + 1, cn = sn >> 3, kn = sn & 7;
      bf16x8* dst = (s & 1) ? efA : efB;
#pragma unroll
      for (int n = 0; n < 4; ++n)
        dst[n] = *(const bf16x8*)(Eb + (cn * 64 + n * 16) * D_ + kn * 32);
    }
    const bf16x8* ef = (s & 1) ? efB : efA;
    bf16x8 zf[4];
#pragma unroll
    for (int m = 0; m < 4; ++m)
      zf[m] = *(const bf16x8*)(zt + (kk * 4 + g) * 512 + (m * 16 + l15) * 8);
#pragma unroll
    for (int m = 0; m < 4; ++m)
#pragma unroll
      for (int n = 0; n < 4; ++n)
        acc[m][n] = __builtin_amdgcn_mfma_f32_16x16x32_bf16(zf[m], ef[n], acc[m][n], 0, 0, 0);

    if (kk == 7) {
      // ph = en - 2*acc. D layout: col=lane&15 (code), row=g*4+r (token).
      const int cb_l = w * 128 + ch * 64;        // local (within half)
      const int cb_f = half * 512 + cb_l;        // full code id
      float enc[4];
#pragma unroll
      for (int n = 0; n < 4; ++n) enc[n] = en_s[cb_l + n * 16 + l15];
#pragma unroll
      for (int m = 0; m < 4; ++m)
#pragma unroll
        for (int n = 0; n < 4; ++n)
#pragma unroll
          for (int r = 0; r < 4; ++r)
            acc[m][n][r] = __builtin_fmaf(-2.0f, acc[m][n][r], enc[n]);
      // per-token chunk-min: 3 fmin + 4 DPP-min (pure VALU), one LDS atomic
#pragma unroll
      for (int m = 0; m < 4; ++m)
#pragma unroll
        for (int r = 0; r < 4; ++r) {
          float v = fminf(fminf(acc[m][0][r], acc[m][1][r]),
                          fminf(acc[m][2][r], acc[m][3][r]));
          v = dppmin<0xB1>(v);     // ^1 (quad_perm 1,0,3,2)
          v = dppmin<0x4E>(v);     // ^2 (quad_perm 2,3,0,1)
          v = dppmin<0x141>(v);    // row_half_mirror (^4 after quads uniform)
          v = dppmin<0x140>(v);    // row_mirror      (^8)
          if (l15 == 0) atomicMin(&rmin_s[m * 16 + g * 4 + r], __float_as_uint(v + 4.0f));
        }
      // triggers: ph <= runmin + M (stale/larger runmin is safe: more triggers)
#pragma unroll
      for (int m = 0; m < 4; ++m)
#pragma unroll
        for (int r = 0; r < 4; ++r) {
          int t = m * 16 + g * 4 + r;
          float thr = (__uint_as_float(rmin_s[t]) - 4.0f) + mg_s[t];
#pragma unroll
          for (int n = 0; n < 4; ++n) {
            if (acc[m][n][r] <= thr) {
              int c = cb_f + n * 16 + l15;
              unsigned pos = atomicAdd(&tcount[w], 1u);
              if (pos < TCAP) tlist[w][pos] = ((unsigned)t << 16) | (unsigned)c;
              else exact_update(zb, E, t, c, zn_s, en_s, best);  // overflow: slow-exact
            }
          }
        }
    }
  }

  // drain own wave's trigger list: exact recompute into global best
  {
    unsigned cnt = tcount[w];
    if (cnt > TCAP) cnt = TCAP;
    for (unsigned basei = 0; basei < cnt; basei += 64) {
      unsigned i = basei + (unsigned)lane;
      if (i < cnt) {
        unsigned e = tlist[w][i];
        exact_update(zb, E, (int)(e >> 16), (int)(e & 1023u), zn_s, en_s, best);
      }
    }
  }
}

// ---------------- z_q_st + loss + embed_sum + idx + counts (all f32) ----------------
__global__ __launch_bounds__(256, 1) void vq_scatter_v8(
    const float* __restrict__ z, const float* __restrict__ E,
    const unsigned long long* __restrict__ best, float* __restrict__ embsum,
    float* __restrict__ loss_sum, float* __restrict__ out_zq,
    float* __restrict__ out_idx, float* __restrict__ counts) {
  __shared__ float zt[256 * 33];     // staged z, overwritten in-place with z_q_st
  __shared__ int idx_s[32];
  __shared__ float wred[4];
  const int tid = threadIdx.x;
  const int tile = blockIdx.x;       // 0..1023
  const int b = tile >> 5;
  const int hw0 = (tile & 31) * 32;
  const float* zb = z + b * (D_ * HW_) + hw0;
  if (tid < 32) {
    int k = (int)(best[b * HW_ + hw0 + tid] & 1023ull);   // in-range by construction
    idx_s[tid] = k;
    out_idx[b * HW_ + hw0 + tid] = (float)k;
    atomicAdd(&counts[k], 1.0f);
  }
#pragma unroll
  for (int r = 0; r < 8; ++r) {
    int ii = r * 256 + tid;
    int d = ii >> 3, t4 = (ii & 7) * 4;
    float4 v = *(const float4*)(zb + d * HW_ + t4);
    float* p = zt + d * 33 + t4;
    p[0] = v.x; p[1] = v.y; p[2] = v.z; p[3] = v.w;
  }
  __syncthreads();

  const int w = tid >> 6, lane = tid & 63;
  float lsum = 0.f;
  for (int tt = 0; tt < 8; ++tt) {
    int t = w * 8 + tt;
    int k = idx_s[t];                      // wave-uniform
    const float* Er = E + k * D_;
    float* es = embsum + k * D_;
#pragma unroll
    for (int i = 0; i < 4; ++i) {
      int d = i * 64 + lane;
      float e = Er[d];
      float zv = zt[d * 33 + t];           // unique (t,d) owner -> safe in-place
      float df = __fsub_rn(zv, e);
      lsum += df * df;
      zt[d * 33 + t] = __fadd_rn(zv, __fsub_rn(e, zv));  // ref: z + (z_q - z)
      atomicAdd(es + d, zv);
    }
  }
#pragma unroll
  for (int o = 32; o > 0; o >>= 1) lsum += __shfl_down(lsum, o, 64);
  if (lane == 0) wred[w] = lsum;
  __syncthreads();
  if (tid == 0) atomicAdd(loss_sum, wred[0] + wred[1] + wred[2] + wred[3]);

  float* ob = out_zq + b * (D_ * HW_) + hw0;
#pragma unroll 4
  for (int r = 0; r < 32; ++r) {
    int d = r * 8 + (tid >> 5);
    int t = tid & 31;
    ob[d * HW_ + t] = zt[d * 33 + t];      // coalesced 128B-chunk f32 stores
  }
}

// ---------------- EMA cluster-size + n + loss finalize ----------------
__global__ void vq_newcs_v7(const float* __restrict__ cs_in, const float* __restrict__ counts,
                            float* __restrict__ newcs, float* __restrict__ nsum,
                            const float* __restrict__ loss_sum,
                            float* __restrict__ out_loss, float* __restrict__ out_ncs) {
  int k = blockIdx.x * 256 + threadIdx.x;
  float v = __fadd_rn(__fmul_rn(0.99f, cs_in[k]), __fmul_rn(0.01f, counts[k]));
  newcs[k] = v;
  out_ncs[k] = v;
  float s = v;
#pragma unroll
  for (int o = 32; o > 0; o >>= 1) s += __shfl_down(s, o, 64);
  __shared__ float w[4];
  if ((threadIdx.x & 63) == 0) w[threadIdx.x >> 6] = s;
  __syncthreads();
  if (threadIdx.x == 0) atomicAdd(nsum, w[0] + w[1] + w[2] + w[3]);
  if (k == 0) out_loss[0] = loss_sum[0] * (1.0f / 8388608.0f);
}

// ---------------- new_es + new_embedding ----------------
__global__ void vq_newemb_v7(const float* __restrict__ es_in, const float* __restrict__ embsum,
                             const float* __restrict__ newcs, const float* __restrict__ nsum,
                             float* __restrict__ out_emb, float* __restrict__ out_nes) {
  int k = blockIdx.x, d = threadIdx.x;
  float n = *nsum;
  float cs = (newcs[k] + 1e-5f) / (n + 1024.0f * 1e-5f) * n;   // ref formula order
  float es = __fadd_rn(__fmul_rn(0.99f, es_in[k * D_ + d]),
                       __fmul_rn(0.01f, embsum[k * D_ + d]));
  out_nes[k * D_ + d] = es;
  out_emb[k * D_ + d] = es / cs;
}

extern "C" void kernel_launch(void* const* d_in, const int* in_sizes, int n_in,
                              void* d_out, int out_size, void* d_ws, size_t ws_size,
                              hipStream_t stream) {
  (void)in_sizes; (void)n_in; (void)out_size; (void)ws_size;
  const float* z       = (const float*)d_in[0];
  const float* E       = (const float*)d_in[1];
  const float* ema_cs  = (const float*)d_in[2];
  const float* ema_es  = (const float*)d_in[3];
  float* out = (float*)d_out;
  char* ws = (char*)d_ws;
  unsigned long long* best = (unsigned long long*)(ws + WS_BEST);
  float* counts = (float*)(ws + WS_COUNTS);
  float* embsum = (float*)(ws + WS_EMBSUM);
  float* loss_s = (float*)(ws + WS_LOSS);
  float* nsum   = (float*)(ws + WS_NSUM);
  unsigned* enmax = (unsigned*)(ws + WS_ENMAX);
  float* newcs  = (float*)(ws + WS_NEWCS);
  float* enorm  = (float*)(ws + WS_ENORM);
  float* znorm  = (float*)(ws + WS_ZNORM);
  u16*   e16    = (u16*)(ws + WS_E16);

  hipMemsetAsync(ws + WS_BEST, 0xFF, 262144, stream);          // best keys = +inf
  hipMemsetAsync(ws + WS_ZERO0, 0, WS_ZEROLEN, stream);        // counts/embsum/loss/nsum/enmax
  vq_norms_v8<<<dim3(264), dim3(128), 0, stream>>>(z, E, znorm, enorm, e16, enmax);
  vq_dist_mfma2<<<dim3(1024), dim3(256), 0, stream>>>(z, E, e16, znorm, enorm, enmax, best);
  vq_scatter_v8<<<dim3(1024), dim3(256), 0, stream>>>(z, E, best, embsum, loss_s,
                                                      out + O_ZQ, out + O_IDX, counts);
  vq_newcs_v7<<<dim3(4), dim3(256), 0, stream>>>(ema_cs, counts, newcs, nsum, loss_s,
                                                 out + O_LOSS, out + O_NCS);
  vq_newemb_v7<<<dim3(K_), dim3(256), 0, stream>>>(ema_es, embsum, newcs, nsum,
                                                   out + O_EMB, out + O_NES);
}

// Round 3
// 390.613 us; speedup vs baseline: 1.1036x; 1.1036x over previous
//
#include <hip/hip_runtime.h>

#define D_  256
#define K_  1024
#define HW_ 1024      // 32*32
#define N_  32768     // 32*HW_

// workspace layout (bytes)
#define WS_BEST    0          // u64[32768]  (memset 0xFF)
#define WS_COUNTS  262144     // f32[1024]
#define WS_EMBSUM  266240     // f32[262144]
#define WS_LOSS    1314816    // f32
#define WS_NSUM    1314820    // f32
#define WS_ENMAX   1314824    // u32 (max ||e||^2 bits)
#define WS_ZERO0   262144     // zero range start
#define WS_ZEROLEN 1052684    // covers counts..enmax
#define WS_NEWCS   1314828    // f32[1024]
#define WS_ENORM   1318924    // f32[1024]
#define WS_ZNORM   1323020    // f32[32768]
#define WS_E16     1454096    // bf16[1024*256] = 512 KiB (16B aligned)
#define WS_TOTAL   1978384

// output offsets (f32 elements): (z_q_st, loss, indices, new_emb, new_cs, new_es)
#define O_ZQ   0
#define O_LOSS 8388608
#define O_IDX  8388609
#define O_EMB  8421377
#define O_NCS  8683521
#define O_NES  8684545

typedef unsigned short u16;
typedef short bf16x8 __attribute__((ext_vector_type(8)));  // 8 bf16 = 4 VGPRs
typedef float f32x4 __attribute__((ext_vector_type(4)));

// round-to-nearest-even f32 -> bf16 (data has no NaN)
__device__ __forceinline__ unsigned bf16rne(float x) {
  unsigned u = __float_as_uint(x);
  return (u + 0x7FFFu + ((u >> 16) & 1u)) >> 16;
}

// numpy pairwise_sum of 256 squares: two 128-halves, 8 accumulators,
// combine ((r0+r1)+(r2+r3))+((r4+r5)+(r6+r7)). __f*_rn blocks FMA contraction.
__device__ __forceinline__ float pw256_sq(const float* __restrict__ p, int stride) {
  float tot0 = 0.f, tot1 = 0.f;
#pragma unroll
  for (int h = 0; h < 2; ++h) {
    const float* q = p + h * 128 * stride;
    float r[8];
#pragma unroll
    for (int j = 0; j < 8; ++j) { float x = q[j * stride]; r[j] = __fmul_rn(x, x); }
    for (int i = 8; i < 128; i += 8)
#pragma unroll
      for (int j = 0; j < 8; ++j) {
        float x = q[(i + j) * stride];
        r[j] = __fadd_rn(r[j], __fmul_rn(x, x));
      }
    float s = __fadd_rn(__fadd_rn(__fadd_rn(r[0], r[1]), __fadd_rn(r[2], r[3])),
                        __fadd_rn(__fadd_rn(r[4], r[5]), __fadd_rn(r[6], r[7])));
    if (h == 0) tot0 = s; else tot1 = s;
  }
  return __fadd_rn(tot0, tot1);
}

// ---------------- ||z_n||^2, ||e_k||^2 (np order), en_max, E->bf16 ----------------
__global__ void vq_norms_v8(const float* __restrict__ z, const float* __restrict__ E,
                            float* __restrict__ znorm, float* __restrict__ enorm,
                            u16* __restrict__ E16, unsigned* __restrict__ enmax) {
  int t = blockIdx.x * 128 + threadIdx.x;        // 264 x 128 = 33792
  if (t < N_) {
    const float* p = z + (t >> 10) * (D_ * HW_) + (t & 1023);  // stride HW_ over d
    znorm[t] = pw256_sq(p, HW_);
  } else if (t < N_ + K_) {
    int k = t - N_;
    float v = pw256_sq(E + k * D_, 1);
    enorm[k] = v;
    atomicMax(enmax, __float_as_uint(v));        // v > 0 -> bit-monotone
  }
  // E -> bf16, element-parallel grid-stride, coalesced pair loads/stores
  unsigned* E16w = (unsigned*)E16;
  int gsz = gridDim.x * 128;
  for (int wd = t; wd < (K_ * D_ / 2); wd += gsz) {
    float2 x = *(const float2*)(E + 2 * wd);
    E16w[wd] = bf16rne(x.x) | (bf16rne(x.y) << 16);
  }
}

// Exact reference-numerics distance for one (token, code): sequential fp32 FMA
// chain over d=0..255 (byte-identical to the v9/reference path), then
// fl(fl(zn - 2a) + en). Key = (score_bits<<32)|code -> device-scope atomicMin
// merges across the two code-half blocks; lowest code wins ties (np argmin).
// noinline: ONE body, not ~130 force-inlined cold copies (I$ is 32 KB).
__device__ __attribute__((noinline)) void exact_update(
    const float* __restrict__ zb, const float* __restrict__ E,
    int t, int c, const float* __restrict__ zn_s, const float* __restrict__ en_s,
    unsigned long long* __restrict__ best) {
  const float* zp = zb + t;             // stride HW_ over d (original f32 z)
  const float* ep = E + c * D_;
  float a = 0.f;
  for (int d0 = 0; d0 < 256; d0 += 8) {
    float zr[8], er[8];
#pragma unroll
    for (int j = 0; j < 8; ++j) { zr[j] = zp[(d0 + j) * HW_]; er[j] = ep[d0 + j]; }
#pragma unroll
    for (int j = 0; j < 8; ++j) a = __fmaf_rn(zr[j], er[j], a);
  }
  float s = __fadd_rn(__fsub_rn(zn_s[t], __fmul_rn(2.0f, a)), en_s[c & 511]);
  // s ~ 200..330 > 0 -> float bits monotone
  unsigned long long key = ((unsigned long long)__float_as_uint(s) << 32) | (unsigned)c;
  atomicMin(&best[t], key);
}

// VALU-speed 16-lane min via DPP (quad_perm ^1, ^2, row_half_mirror, row_mirror)
template <int CTRL>
__device__ __forceinline__ float dppmin(float v) {
  int p = __builtin_amdgcn_update_dpp(0, __float_as_int(v), CTRL, 0xF, 0xF, true);
  return fminf(v, __int_as_float(p));
}

#define TCAP 192   // per-wave trigger-list capacity (expected ~40-100 used)

// ---------------- MFMA distance + argmin with exact verification ----------------
// 1024 blocks x 256 thr, 4 blocks/CU (16 waves/CU). Block = 64 tokens x 512
// codes (blockIdx&1 = code half). Wave owns 128 codes in 4 chunks of 32:
// acc[4][2] = 32 regs (NOT 64) so the whole wave fits the 128-reg cap of
// launch_bounds(256,4) without spilling (round-2 failure mode).
// bf16 MFMA approx scores ph = en - 2*(z.e); block-local running min per token
// (LDS atomicMin on ph+4 bits); any ph within margin M of runmin is exactly
// recomputed into the GLOBAL best[] key (merged across halves by atomicMin).
// M = 2^-4*sqrt(zn*en_max)+2e-4 = 2x the worst-case two-sided bf16 error bound,
// so the reference argmin always triggers in its own half-block.
__global__ __launch_bounds__(256, 4) void vq_dist_mfma3(
    const float* __restrict__ z, const float* __restrict__ E,
    const u16* __restrict__ E16,
    const float* __restrict__ znorm, const float* __restrict__ enorm,
    const unsigned* __restrict__ enmax,
    unsigned long long* __restrict__ best_g) {
  // z tile as bf16 in [kb=d>>3][tok][8d] subtiles: frag ds_read_b128 is
  // conflict-free (16 lanes -> 16 consecutive 16B slots per quarter-wave).
  __shared__ __align__(16) u16 zt[32 * 64 * 8];          // 32 KiB
  __shared__ float en_s[512];                             // this half's norms
  __shared__ float zn_s[64];
  __shared__ float mg_s[64];
  __shared__ unsigned rmin_s[64];                         // bits of (min ph)+4.0
  __shared__ unsigned tcount[4];
  __shared__ unsigned tlist[4][TCAP];                     // 3 KiB

  const int tid = threadIdx.x;
  const int tile = blockIdx.x >> 1;          // 0..511 (token tile)
  const int half = blockIdx.x & 1;           // code half
  const int bimg = tile >> 4;
  const int hw0 = (tile & 15) << 6;
  const float* zb = z + bimg * (D_ * HW_) + hw0;
  unsigned long long* best = best_g + bimg * HW_ + hw0;

  if (tid < 64) {
    float zn = znorm[bimg * HW_ + hw0 + tid];
    zn_s[tid] = zn;
    float em = __uint_as_float(*enmax);
    mg_s[tid] = 0.0625f * sqrtf(zn * em) + 2e-4f;   // margin M (proven safe)
    rmin_s[tid] = 0xFFFFFFFFu;                       // own-chunk min lands before use
  }
  if (tid < 4) tcount[tid] = 0;
  for (int i = tid; i < 512; i += 256) en_s[i] = enorm[half * 512 + i];

  // stage z tile -> bf16 LDS. thread: tok = tid&63, kb = (tid>>6)*8 + r.
  // global: 64 lanes read 64 consecutive floats per instr (256B coalesced).
  {
    const int tok = tid & 63;
    const int kbase = (tid >> 6) * 8;
    for (int r = 0; r < 8; ++r) {
      int kb = kbase + r;
      unsigned pk[4];
#pragma unroll
      for (int j = 0; j < 4; ++j) {
        float x0 = zb[(kb * 8 + 2 * j) * HW_ + tok];
        float x1 = zb[(kb * 8 + 2 * j + 1) * HW_ + tok];
        pk[j] = bf16rne(x0) | (bf16rne(x1) << 16);
      }
      uint4 wv; wv.x = pk[0]; wv.y = pk[1]; wv.z = pk[2]; wv.w = pk[3];
      *(uint4*)(zt + kb * 512 + tok * 8) = wv;       // 16B, conflict-free
    }
  }
  __syncthreads();

  const int lane = tid & 63;
  const int w = tid >> 6;
  const int l15 = lane & 15, g = lane >> 4;
  // B-frag base: row = code (l15), k-slice col = g*8; chunk/n/kk add offsets
  const u16* Eb = E16 + (unsigned)(half * 512 + w * 128 + l15) * D_ + g * 8;

  // 32 steps = 4 chunks x 8 kk, fully unrolled; ef register ping-pong (2 frags):
  // loads for step s+1 issue before step s's 8 MFMAs.
  bf16x8 efA[2], efB[2];
#pragma unroll
  for (int n = 0; n < 2; ++n)
    efA[n] = *(const bf16x8*)(Eb + n * 16 * D_);          // s=0: ch=0,kk=0

  f32x4 acc[4][2];
#pragma unroll
  for (int s = 0; s < 32; ++s) {
    const int ch = s >> 3, kk = s & 7;
    if (kk == 0) {
      f32x4 z4 = {0.f, 0.f, 0.f, 0.f};
#pragma unroll
      for (int m = 0; m < 4; ++m)
#pragma unroll
        for (int n = 0; n < 2; ++n) acc[m][n] = z4;
    }
    if (s < 31) {
      const int sn = s + 1, cn = sn >> 3, kn = sn & 7;
      bf16x8* dst = (s & 1) ? efA : efB;
#pragma unroll
      for (int n = 0; n < 2; ++n)
        dst[n] = *(const bf16x8*)(Eb + (cn * 32 + n * 16) * D_ + kn * 32);
    }
    const bf16x8* ef = (s & 1) ? efB : efA;
    bf16x8 zf[4];
#pragma unroll
    for (int m = 0; m < 4; ++m)
      zf[m] = *(const bf16x8*)(zt + (kk * 4 + g) * 512 + (m * 16 + l15) * 8);
#pragma unroll
    for (int m = 0; m < 4; ++m)
#pragma unroll
      for (int n = 0; n < 2; ++n)
        acc[m][n] = __builtin_amdgcn_mfma_f32_16x16x32_bf16(zf[m], ef[n], acc[m][n], 0, 0, 0);

    if (kk == 7) {
      // ph = en - 2*acc. D layout: col=lane&15 (code), row=g*4+r (token).
      const int cb_l = w * 128 + ch * 32;        // local (within half)
      const int cb_f = half * 512 + cb_l;        // full code id
      float enc[2];
#pragma unroll
      for (int n = 0; n < 2; ++n) enc[n] = en_s[cb_l + n * 16 + l15];
#pragma unroll
      for (int m = 0; m < 4; ++m)
#pragma unroll
        for (int n = 0; n < 2; ++n)
#pragma unroll
          for (int r = 0; r < 4; ++r)
            acc[m][n][r] = __builtin_fmaf(-2.0f, acc[m][n][r], enc[n]);
      // per-token chunk-min: 1 fmin + 4 DPP-min (pure VALU), one LDS atomic
#pragma unroll
      for (int m = 0; m < 4; ++m)
#pragma unroll
        for (int r = 0; r < 4; ++r) {
          float v = fminf(acc[m][0][r], acc[m][1][r]);
          v = dppmin<0xB1>(v);     // ^1 (quad_perm 1,0,3,2)
          v = dppmin<0x4E>(v);     // ^2 (quad_perm 2,3,0,1)
          v = dppmin<0x141>(v);    // row_half_mirror
          v = dppmin<0x140>(v);    // row_mirror
          if (l15 == 0) atomicMin(&rmin_s[m * 16 + g * 4 + r], __float_as_uint(v + 4.0f));
        }
      // triggers: ph <= runmin + M (stale/larger runmin is safe: more triggers)
#pragma unroll
      for (int m = 0; m < 4; ++m)
#pragma unroll
        for (int r = 0; r < 4; ++r) {
          int t = m * 16 + g * 4 + r;
          float thr = (__uint_as_float(rmin_s[t]) - 4.0f) + mg_s[t];
#pragma unroll
          for (int n = 0; n < 2; ++n) {
            if (acc[m][n][r] <= thr) {
              int c = cb_f + n * 16 + l15;
              unsigned pos = atomicAdd(&tcount[w], 1u);
              if (pos < TCAP) tlist[w][pos] = ((unsigned)t << 16) | (unsigned)c;
              else exact_update(zb, E, t, c, zn_s, en_s, best);  // overflow: slow-exact
            }
          }
        }
    }
  }

  // drain own wave's trigger list: exact recompute into global best
  {
    unsigned cnt = tcount[w];
    if (cnt > TCAP) cnt = TCAP;
    for (unsigned basei = 0; basei < cnt; basei += 64) {
      unsigned i = basei + (unsigned)lane;
      if (i < cnt) {
        unsigned e = tlist[w][i];
        exact_update(zb, E, (int)(e >> 16), (int)(e & 1023u), zn_s, en_s, best);
      }
    }
  }
}

// ---------------- z_q_st + loss + embed_sum + idx + counts (all f32) ----------------
__global__ __launch_bounds__(256, 1) void vq_scatter_v8(
    const float* __restrict__ z, const float* __restrict__ E,
    const unsigned long long* __restrict__ best, float* __restrict__ embsum,
    float* __restrict__ loss_sum, float* __restrict__ out_zq,
    float* __restrict__ out_idx, float* __restrict__ counts) {
  __shared__ float zt[256 * 33];     // staged z, overwritten in-place with z_q_st
  __shared__ int idx_s[32];
  __shared__ float wred[4];
  const int tid = threadIdx.x;
  const int tile = blockIdx.x;       // 0..1023
  const int b = tile >> 5;
  const int hw0 = (tile & 31) * 32;
  const float* zb = z + b * (D_ * HW_) + hw0;
  if (tid < 32) {
    int k = (int)(best[b * HW_ + hw0 + tid] & 1023ull);   // in-range by construction
    idx_s[tid] = k;
    out_idx[b * HW_ + hw0 + tid] = (float)k;
    atomicAdd(&counts[k], 1.0f);
  }
#pragma unroll
  for (int r = 0; r < 8; ++r) {
    int ii = r * 256 + tid;
    int d = ii >> 3, t4 = (ii & 7) * 4;
    float4 v = *(const float4*)(zb + d * HW_ + t4);
    float* p = zt + d * 33 + t4;
    p[0] = v.x; p[1] = v.y; p[2] = v.z; p[3] = v.w;
  }
  __syncthreads();

  const int w = tid >> 6, lane = tid & 63;
  float lsum = 0.f;
  for (int tt = 0; tt < 8; ++tt) {
    int t = w * 8 + tt;
    int k = idx_s[t];                      // wave-uniform
    const float* Er = E + k * D_;
    float* es = embsum + k * D_;
#pragma unroll
    for (int i = 0; i < 4; ++i) {
      int d = i * 64 + lane;
      float e = Er[d];
      float zv = zt[d * 33 + t];           // unique (t,d) owner -> safe in-place
      float df = __fsub_rn(zv, e);
      lsum += df * df;
      zt[d * 33 + t] = __fadd_rn(zv, __fsub_rn(e, zv));  // ref: z + (z_q - z)
      atomicAdd(es + d, zv);
    }
  }
#pragma unroll
  for (int o = 32; o > 0; o >>= 1) lsum += __shfl_down(lsum, o, 64);
  if (lane == 0) wred[w] = lsum;
  __syncthreads();
  if (tid == 0) atomicAdd(loss_sum, wred[0] + wred[1] + wred[2] + wred[3]);

  float* ob = out_zq + b * (D_ * HW_) + hw0;
#pragma unroll 4
  for (int r = 0; r < 32; ++r) {
    int d = r * 8 + (tid >> 5);
    int t = tid & 31;
    ob[d * HW_ + t] = zt[d * 33 + t];      // coalesced 128B-chunk f32 stores
  }
}

// ---------------- EMA cluster-size + n + loss finalize ----------------
__global__ void vq_newcs_v7(const float* __restrict__ cs_in, const float* __restrict__ counts,
                            float* __restrict__ newcs, float* __restrict__ nsum,
                            const float* __restrict__ loss_sum,
                            float* __restrict__ out_loss, float* __restrict__ out_ncs) {
  int k = blockIdx.x * 256 + threadIdx.x;
  float v = __fadd_rn(__fmul_rn(0.99f, cs_in[k]), __fmul_rn(0.01f, counts[k]));
  newcs[k] = v;
  out_ncs[k] = v;
  float s = v;
#pragma unroll
  for (int o = 32; o > 0; o >>= 1) s += __shfl_down(s, o, 64);
  __shared__ float w[4];
  if ((threadIdx.x & 63) == 0) w[threadIdx.x >> 6] = s;
  __syncthreads();
  if (threadIdx.x == 0) atomicAdd(nsum, w[0] + w[1] + w[2] + w[3]);
  if (k == 0) out_loss[0] = loss_sum[0] * (1.0f / 8388608.0f);
}

// ---------------- new_es + new_embedding ----------------
__global__ void vq_newemb_v7(const float* __restrict__ es_in, const float* __restrict__ embsum,
                             const float* __restrict__ newcs, const float* __restrict__ nsum,
                             float* __restrict__ out_emb, float* __restrict__ out_nes) {
  int k = blockIdx.x, d = threadIdx.x;
  float n = *nsum;
  float cs = (newcs[k] + 1e-5f) / (n + 1024.0f * 1e-5f) * n;   // ref formula order
  float es = __fadd_rn(__fmul_rn(0.99f, es_in[k * D_ + d]),
                       __fmul_rn(0.01f, embsum[k * D_ + d]));
  out_nes[k * D_ + d] = es;
  out_emb[k * D_ + d] = es / cs;
}

extern "C" void kernel_launch(void* const* d_in, const int* in_sizes, int n_in,
                              void* d_out, int out_size, void* d_ws, size_t ws_size,
                              hipStream_t stream) {
  (void)in_sizes; (void)n_in; (void)out_size; (void)ws_size;
  const float* z       = (const float*)d_in[0];
  const float* E       = (const float*)d_in[1];
  const float* ema_cs  = (const float*)d_in[2];
  const float* ema_es  = (const float*)d_in[3];
  float* out = (float*)d_out;
  char* ws = (char*)d_ws;
  unsigned long long* best = (unsigned long long*)(ws + WS_BEST);
  float* counts = (float*)(ws + WS_COUNTS);
  float* embsum = (float*)(ws + WS_EMBSUM);
  float* loss_s = (float*)(ws + WS_LOSS);
  float* nsum   = (float*)(ws + WS_NSUM);
  unsigned* enmax = (unsigned*)(ws + WS_ENMAX);
  float* newcs  = (float*)(ws + WS_NEWCS);
  float* enorm  = (float*)(ws + WS_ENORM);
  float* znorm  = (float*)(ws + WS_ZNORM);
  u16*   e16    = (u16*)(ws + WS_E16);

  hipMemsetAsync(ws + WS_BEST, 0xFF, 262144, stream);          // best keys = +inf
  hipMemsetAsync(ws + WS_ZERO0, 0, WS_ZEROLEN, stream);        // counts/embsum/loss/nsum/enmax
  vq_norms_v8<<<dim3(264), dim3(128), 0, stream>>>(z, E, znorm, enorm, e16, enmax);
  vq_dist_mfma3<<<dim3(1024), dim3(256), 0, stream>>>(z, E, e16, znorm, enorm, enmax, best);
  vq_scatter_v8<<<dim3(1024), dim3(256), 0, stream>>>(z, E, best, embsum, loss_s,
                                                      out + O_ZQ, out + O_IDX, counts);
  vq_newcs_v7<<<dim3(4), dim3(256), 0, stream>>>(ema_cs, counts, newcs, nsum, loss_s,
                                                 out + O_LOSS, out + O_NCS);
  vq_newemb_v7<<<dim3(K_), dim3(256), 0, stream>>>(ema_es, embsum, newcs, nsum,
                                                   out + O_EMB, out + O_NES);
}

// Round 4
// 372.662 us; speedup vs baseline: 1.1568x; 1.0482x over previous
//
#include <hip/hip_runtime.h>

#define D_  256
#define K_  1024
#define HW_ 1024      // 32*32
#define N_  32768     // 32*HW_

// workspace layout (bytes)
#define WS_BEST    0          // u64[32768]  (memset 0xFF)
#define WS_COUNTS  262144     // f32[1024]
#define WS_EMBSUM  266240     // f32[262144]
#define WS_LOSS    1314816    // f32
#define WS_NSUM    1314820    // f32
#define WS_ENMAX   1314824    // u32 (max ||e||^2 bits)
#define WS_ZERO0   262144     // zero range start
#define WS_ZEROLEN 1052684    // covers counts..enmax
#define WS_NEWCS   1314828    // f32[1024]
#define WS_ENORM   1318924    // f32[1024]
#define WS_ZNORM   1323020    // f32[32768]
#define WS_E16     1454096    // bf16[1024*256] = 512 KiB (16B aligned)
#define WS_TOTAL   1978384

// output offsets (f32 elements): (z_q_st, loss, indices, new_emb, new_cs, new_es)
#define O_ZQ   0
#define O_LOSS 8388608
#define O_IDX  8388609
#define O_EMB  8421377
#define O_NCS  8683521
#define O_NES  8684545

typedef unsigned short u16;
typedef short bf16x8 __attribute__((ext_vector_type(8)));  // 8 bf16 = 4 VGPRs
typedef float f32x4 __attribute__((ext_vector_type(4)));

// round-to-nearest-even f32 -> bf16 (data has no NaN)
__device__ __forceinline__ unsigned bf16rne(float x) {
  unsigned u = __float_as_uint(x);
  return (u + 0x7FFFu + ((u >> 16) & 1u)) >> 16;
}

// numpy pairwise_sum of 256 squares: two 128-halves, 8 accumulators,
// combine ((r0+r1)+(r2+r3))+((r4+r5)+(r6+r7)). __f*_rn blocks FMA contraction.
__device__ __forceinline__ float pw256_sq(const float* __restrict__ p, int stride) {
  float tot0 = 0.f, tot1 = 0.f;
#pragma unroll
  for (int h = 0; h < 2; ++h) {
    const float* q = p + h * 128 * stride;
    float r[8];
#pragma unroll
    for (int j = 0; j < 8; ++j) { float x = q[j * stride]; r[j] = __fmul_rn(x, x); }
    for (int i = 8; i < 128; i += 8)
#pragma unroll
      for (int j = 0; j < 8; ++j) {
        float x = q[(i + j) * stride];
        r[j] = __fadd_rn(r[j], __fmul_rn(x, x));
      }
    float s = __fadd_rn(__fadd_rn(__fadd_rn(r[0], r[1]), __fadd_rn(r[2], r[3])),
                        __fadd_rn(__fadd_rn(r[4], r[5]), __fadd_rn(r[6], r[7])));
    if (h == 0) tot0 = s; else tot1 = s;
  }
  return __fadd_rn(tot0, tot1);
}

// ---------------- ||z_n||^2, ||e_k||^2 (np order), en_max, E->bf16 ----------------
__global__ void vq_norms_v8(const float* __restrict__ z, const float* __restrict__ E,
                            float* __restrict__ znorm, float* __restrict__ enorm,
                            u16* __restrict__ E16, unsigned* __restrict__ enmax) {
  int t = blockIdx.x * 128 + threadIdx.x;        // 264 x 128 = 33792
  if (t < N_) {
    const float* p = z + (t >> 10) * (D_ * HW_) + (t & 1023);  // stride HW_ over d
    znorm[t] = pw256_sq(p, HW_);
  } else if (t < N_ + K_) {
    int k = t - N_;
    float v = pw256_sq(E + k * D_, 1);
    enorm[k] = v;
    atomicMax(enmax, __float_as_uint(v));        // v > 0 -> bit-monotone
  }
  // E -> bf16, element-parallel grid-stride, coalesced pair loads/stores
  unsigned* E16w = (unsigned*)E16;
  int gsz = gridDim.x * 128;
  for (int wd = t; wd < (K_ * D_ / 2); wd += gsz) {
    float2 x = *(const float2*)(E + 2 * wd);
    E16w[wd] = bf16rne(x.x) | (bf16rne(x.y) << 16);
  }
}

// Exact reference-numerics distance for one (token, code): sequential fp32 FMA
// chain over d=0..255 (byte-identical to the v9/reference path), then
// fl(fl(zn - 2a) + en). Key = (score_bits<<32)|code -> device-scope atomicMin
// merges across the two code-half blocks; lowest code wins ties (np argmin).
// noinline is SAFE here: only called AFTER the MFMA main loop (no live acc/ef
// across call sites -> no RA poison), and keeps the kernel I$-compact.
__device__ __attribute__((noinline)) void exact_update(
    const float* __restrict__ zb, const float* __restrict__ E,
    int t, int c, const float* __restrict__ zn_s, const float* __restrict__ en_s,
    unsigned long long* __restrict__ best) {
  const float* zp = zb + t;             // stride HW_ over d (original f32 z)
  const float* ep = E + c * D_;
  float a = 0.f;
  for (int d0 = 0; d0 < 256; d0 += 8) {
    float zr[8], er[8];
#pragma unroll
    for (int j = 0; j < 8; ++j) { zr[j] = zp[(d0 + j) * HW_]; er[j] = ep[d0 + j]; }
#pragma unroll
    for (int j = 0; j < 8; ++j) a = __fmaf_rn(zr[j], er[j], a);
  }
  float s = __fadd_rn(__fsub_rn(zn_s[t], __fmul_rn(2.0f, a)), en_s[c & 511]);
  // s ~ 200..330 > 0 -> float bits monotone
  unsigned long long key = ((unsigned long long)__float_as_uint(s) << 32) | (unsigned)c;
  atomicMin(&best[t], key);
}

// VALU-speed 16-lane min via DPP (quad_perm ^1, ^2, row_half_mirror, row_mirror)
template <int CTRL>
__device__ __forceinline__ float dppmin(float v) {
  int p = __builtin_amdgcn_update_dpp(0, __float_as_int(v), CTRL, 0xF, 0xF, true);
  return fminf(v, __int_as_float(p));
}

#define TCAP 288   // per-wave trigger-list capacity (expected ~130 used)

// ---------------- MFMA distance + argmin with exact verification ----------------
// 1024 blocks x 256 thr, 4 blocks/CU. Block = 64 tokens x 512 codes.
// XCD-pair swizzle: the two code-halves of one token tile are blockIdx b and
// b+8 -> same XCD -> second half's z staging hits that XCD's L2.
// Wave owns 128 codes in 4 chunks of 32 (acc[4][2] = 32 regs). Main loop is
// ROLLED (16 iters, manual unroll-by-2 for static ef ping-pong) and contains
// ZERO function calls (round-3 failure: noinline calls inside the unrolled
// loop poisoned regalloc -> 29 MB scratch spill at VGPR_Count=64).
// bf16 MFMA approx scores ph = en - 2*(z.e); block-local running min per token
// (LDS atomicMin on ph+4 bits); any ph within margin M of runmin is listed and
// exactly recomputed after the loop into the GLOBAL best[] key.
// M = 2^-4*sqrt(zn*en_max)+2e-4 = 2x the worst-case two-sided bf16 error bound,
// so the reference argmin always triggers in its own half-block. TCAP overflow
// (never in practice) -> that wave exactly re-verifies its full 64x128 tile.
__global__ __launch_bounds__(256, 4) void vq_dist_mfma4(
    const float* __restrict__ z, const float* __restrict__ E,
    const u16* __restrict__ E16,
    const float* __restrict__ znorm, const float* __restrict__ enorm,
    const unsigned* __restrict__ enmax,
    unsigned long long* __restrict__ best_g) {
  // z tile as bf16 in [kb=d>>3][tok][8d] subtiles: frag ds_read_b128 is
  // conflict-free (16 lanes -> 16 consecutive 16B slots per quarter-wave).
  __shared__ __align__(16) u16 zt[32 * 64 * 8];          // 32 KiB
  __shared__ float en_s[512];                             // this half's norms
  __shared__ float zn_s[64];
  __shared__ float mg_s[64];
  __shared__ unsigned rmin_s[64];                         // bits of (min ph)+4.0
  __shared__ unsigned tcount[4];
  __shared__ unsigned tlist[4][TCAP];

  const int tid = threadIdx.x;
  const int b = blockIdx.x;
  const int tile = (b & 7) | ((b >> 4) << 3);  // 0..511 (token tile)
  const int half = (b >> 3) & 1;               // code half; pair = b, b+8
  const int bimg = tile >> 4;
  const int hw0 = (tile & 15) << 6;
  const float* zb = z + bimg * (D_ * HW_) + hw0;
  unsigned long long* best = best_g + bimg * HW_ + hw0;

  if (tid < 64) {
    float zn = znorm[bimg * HW_ + hw0 + tid];
    zn_s[tid] = zn;
    float em = __uint_as_float(*enmax);
    mg_s[tid] = 0.0625f * sqrtf(zn * em) + 2e-4f;   // margin M (proven safe)
    rmin_s[tid] = 0xFFFFFFFFu;   // own-wave chunk-min always lands before read
  }
  if (tid < 4) tcount[tid] = 0;
  for (int i = tid; i < 512; i += 256) en_s[i] = enorm[half * 512 + i];

  // stage z tile -> bf16 LDS. thread: tok = tid&63, kb = (tid>>6)*8 + r.
  // global: 64 lanes read 64 consecutive floats per instr (256B coalesced).
  {
    const int tok = tid & 63;
    const int kbase = (tid >> 6) * 8;
    for (int r = 0; r < 8; ++r) {
      int kb = kbase + r;
      unsigned pk[4];
#pragma unroll
      for (int j = 0; j < 4; ++j) {
        float x0 = zb[(kb * 8 + 2 * j) * HW_ + tok];
        float x1 = zb[(kb * 8 + 2 * j + 1) * HW_ + tok];
        pk[j] = bf16rne(x0) | (bf16rne(x1) << 16);
      }
      uint4 wv; wv.x = pk[0]; wv.y = pk[1]; wv.z = pk[2]; wv.w = pk[3];
      *(uint4*)(zt + kb * 512 + tok * 8) = wv;       // 16B, conflict-free
    }
  }
  __syncthreads();

  const int lane = tid & 63;
  const int w = tid >> 6;
  const int l15 = lane & 15, g = lane >> 4;
  // B-frag base: row = code (l15), k-slice col = g*8; chunk/n/kk add offsets
  const u16* Eb = E16 + (unsigned)(half * 512 + w * 128 + l15) * D_ + g * 8;

  bf16x8 efA[2], efB[2];
#pragma unroll
  for (int n = 0; n < 2; ++n)
    efA[n] = *(const bf16x8*)(Eb + n * 16 * D_);          // prime: s=0 (ch0,kk0)

  f32x4 acc[4][2];

// one MFMA step: S = step id (runtime), EFU = ef bank consumed (loaded at S-1),
// EFF = ef bank filled for step SN. Pure loads/MFMA — no branches, no calls.
#define MSTEP(S, EFU, EFF, SN)                                                   \
  {                                                                              \
    const int kk_ = (S) & 7;                                                     \
    {                                                                            \
      const int cn_ = (SN) >> 3, kn_ = (SN) & 7;                                 \
      _Pragma("unroll")                                                          \
      for (int n = 0; n < 2; ++n)                                                \
        EFF[n] = *(const bf16x8*)(Eb + (cn_ * 32 + n * 16) * D_ + kn_ * 32);     \
    }                                                                            \
    bf16x8 zf_[4];                                                               \
    _Pragma("unroll")                                                            \
    for (int m = 0; m < 4; ++m)                                                  \
      zf_[m] = *(const bf16x8*)(zt + (kk_ * 4 + g) * 512 + (m * 16 + l15) * 8);  \
    _Pragma("unroll")                                                            \
    for (int m = 0; m < 4; ++m)                                                  \
      _Pragma("unroll")                                                          \
      for (int n = 0; n < 2; ++n)                                                \
        acc[m][n] = __builtin_amdgcn_mfma_f32_16x16x32_bf16(zf_[m], EFU[n],      \
                                                            acc[m][n], 0, 0, 0); \
  }

  for (int s2 = 0; s2 < 32; s2 += 2) {
    if ((s2 & 7) == 0) {               // chunk start: zero accumulators
      f32x4 z4 = {0.f, 0.f, 0.f, 0.f};
#pragma unroll
      for (int m = 0; m < 4; ++m)
#pragma unroll
        for (int n = 0; n < 2; ++n) acc[m][n] = z4;
    }
    MSTEP(s2, efA, efB, s2 + 1)                       // even step: use A, fill B
    MSTEP(s2 + 1, efB, efA, (s2 + 2) & 31)            // odd: use B, fill A (s2=30
                                                      //  wraps; wrapped never used)
    if (((s2 + 1) & 7) == 7) {         // chunk end (s = 7,15,23,31): epilogue
      const int ch = s2 >> 3;
      const int cb_l = w * 128 + ch * 32;        // local (within half)
      const int cb_f = half * 512 + cb_l;        // full code id
      // ph = en - 2*acc. D layout: col=lane&15 (code), row=g*4+r (token).
      float enc[2];
#pragma unroll
      for (int n = 0; n < 2; ++n) enc[n] = en_s[cb_l + n * 16 + l15];
#pragma unroll
      for (int m = 0; m < 4; ++m)
#pragma unroll
        for (int n = 0; n < 2; ++n)
#pragma unroll
          for (int r = 0; r < 4; ++r)
            acc[m][n][r] = __builtin_fmaf(-2.0f, acc[m][n][r], enc[n]);
      // per-token chunk-min: 1 fmin + 4 DPP-min (pure VALU), one LDS atomic
#pragma unroll
      for (int m = 0; m < 4; ++m)
#pragma unroll
        for (int r = 0; r < 4; ++r) {
          float v = fminf(acc[m][0][r], acc[m][1][r]);
          v = dppmin<0xB1>(v);     // ^1 (quad_perm 1,0,3,2)
          v = dppmin<0x4E>(v);     // ^2 (quad_perm 2,3,0,1)
          v = dppmin<0x141>(v);    // row_half_mirror
          v = dppmin<0x140>(v);    // row_mirror
          if (l15 == 0) atomicMin(&rmin_s[m * 16 + g * 4 + r], __float_as_uint(v + 4.0f));
        }
      // triggers: ph <= runmin + M (stale/larger runmin safe: more triggers).
      // Overflow entries are DROPPED but counted -> post-loop full re-verify.
#pragma unroll
      for (int m = 0; m < 4; ++m)
#pragma unroll
        for (int r = 0; r < 4; ++r) {
          int t = m * 16 + g * 4 + r;
          float thr = (__uint_as_float(rmin_s[t]) - 4.0f) + mg_s[t];
#pragma unroll
          for (int n = 0; n < 2; ++n) {
            if (acc[m][n][r] <= thr) {
              unsigned pos = atomicAdd(&tcount[w], 1u);
              if (pos < TCAP)
                tlist[w][pos] = ((unsigned)t << 16) | (unsigned)(cb_f + n * 16 + l15);
            }
          }
        }
    }
  }
#undef MSTEP

  // drain own wave's trigger list: exact recompute into global best
  {
    unsigned cnt = tcount[w];
    if (cnt <= TCAP) {
      for (unsigned basei = 0; basei < cnt; basei += 64) {
        unsigned i = basei + (unsigned)lane;
        if (i < cnt) {
          unsigned e = tlist[w][i];
          exact_update(zb, E, (int)(e >> 16), (int)(e & 1023u), zn_s, en_s, best);
        }
      }
    } else {
      // overflow (astronomically rare): exactly verify this wave's whole tile
      const int c0 = half * 512 + w * 128;
      for (unsigned i = (unsigned)lane; i < 64u * 128u; i += 64) {
        exact_update(zb, E, (int)(i >> 7), c0 + (int)(i & 127u), zn_s, en_s, best);
      }
    }
  }
}

// ---------------- z_q_st + loss + embed_sum + idx + counts (all f32) ----------------
__global__ __launch_bounds__(256, 1) void vq_scatter_v8(
    const float* __restrict__ z, const float* __restrict__ E,
    const unsigned long long* __restrict__ best, float* __restrict__ embsum,
    float* __restrict__ loss_sum, float* __restrict__ out_zq,
    float* __restrict__ out_idx, float* __restrict__ counts) {
  __shared__ float zt[256 * 33];     // staged z, overwritten in-place with z_q_st
  __shared__ int idx_s[32];
  __shared__ float wred[4];
  const int tid = threadIdx.x;
  const int tile = blockIdx.x;       // 0..1023
  const int b = tile >> 5;
  const int hw0 = (tile & 31) * 32;
  const float* zb = z + b * (D_ * HW_) + hw0;
  if (tid < 32) {
    int k = (int)(best[b * HW_ + hw0 + tid] & 1023ull);   // in-range by construction
    idx_s[tid] = k;
    out_idx[b * HW_ + hw0 + tid] = (float)k;
    atomicAdd(&counts[k], 1.0f);
  }
#pragma unroll
  for (int r = 0; r < 8; ++r) {
    int ii = r * 256 + tid;
    int d = ii >> 3, t4 = (ii & 7) * 4;
    float4 v = *(const float4*)(zb + d * HW_ + t4);
    float* p = zt + d * 33 + t4;
    p[0] = v.x; p[1] = v.y; p[2] = v.z; p[3] = v.w;
  }
  __syncthreads();

  const int w = tid >> 6, lane = tid & 63;
  float lsum = 0.f;
  for (int tt = 0; tt < 8; ++tt) {
    int t = w * 8 + tt;
    int k = idx_s[t];                      // wave-uniform
    const float* Er = E + k * D_;
    float* es = embsum + k * D_;
#pragma unroll
    for (int i = 0; i < 4; ++i) {
      int d = i * 64 + lane;
      float e = Er[d];
      float zv = zt[d * 33 + t];           // unique (t,d) owner -> safe in-place
      float df = __fsub_rn(zv, e);
      lsum += df * df;
      zt[d * 33 + t] = __fadd_rn(zv, __fsub_rn(e, zv));  // ref: z + (z_q - z)
      atomicAdd(es + d, zv);
    }
  }
#pragma unroll
  for (int o = 32; o > 0; o >>= 1) lsum += __shfl_down(lsum, o, 64);
  if (lane == 0) wred[w] = lsum;
  __syncthreads();
  if (tid == 0) atomicAdd(loss_sum, wred[0] + wred[1] + wred[2] + wred[3]);

  float* ob = out_zq + b * (D_ * HW_) + hw0;
#pragma unroll 4
  for (int r = 0; r < 32; ++r) {
    int d = r * 8 + (tid >> 5);
    int t = tid & 31;
    ob[d * HW_ + t] = zt[d * 33 + t];      // coalesced 128B-chunk f32 stores
  }
}

// ---------------- EMA cluster-size + n + loss finalize ----------------
__global__ void vq_newcs_v7(const float* __restrict__ cs_in, const float* __restrict__ counts,
                            float* __restrict__ newcs, float* __restrict__ nsum,
                            const float* __restrict__ loss_sum,
                            float* __restrict__ out_loss, float* __restrict__ out_ncs) {
  int k = blockIdx.x * 256 + threadIdx.x;
  float v = __fadd_rn(__fmul_rn(0.99f, cs_in[k]), __fmul_rn(0.01f, counts[k]));
  newcs[k] = v;
  out_ncs[k] = v;
  float s = v;
#pragma unroll
  for (int o = 32; o > 0; o >>= 1) s += __shfl_down(s, o, 64);
  __shared__ float w[4];
  if ((threadIdx.x & 63) == 0) w[threadIdx.x >> 6] = s;
  __syncthreads();
  if (threadIdx.x == 0) atomicAdd(nsum, w[0] + w[1] + w[2] + w[3]);
  if (k == 0) out_loss[0] = loss_sum[0] * (1.0f / 8388608.0f);
}

// ---------------- new_es + new_embedding ----------------
__global__ void vq_newemb_v7(const float* __restrict__ es_in, const float* __restrict__ embsum,
                             const float* __restrict__ newcs, const float* __restrict__ nsum,
                             float* __restrict__ out_emb, float* __restrict__ out_nes) {
  int k = blockIdx.x, d = threadIdx.x;
  float n = *nsum;
  float cs = (newcs[k] + 1e-5f) / (n + 1024.0f * 1e-5f) * n;   // ref formula order
  float es = __fadd_rn(__fmul_rn(0.99f, es_in[k * D_ + d]),
                       __fmul_rn(0.01f, embsum[k * D_ + d]));
  out_nes[k * D_ + d] = es;
  out_emb[k * D_ + d] = es / cs;
}

extern "C" void kernel_launch(void* const* d_in, const int* in_sizes, int n_in,
                              void* d_out, int out_size, void* d_ws, size_t ws_size,
                              hipStream_t stream) {
  (void)in_sizes; (void)n_in; (void)out_size; (void)ws_size;
  const float* z       = (const float*)d_in[0];
  const float* E       = (const float*)d_in[1];
  const float* ema_cs  = (const float*)d_in[2];
  const float* ema_es  = (const float*)d_in[3];
  float* out = (float*)d_out;
  char* ws = (char*)d_ws;
  unsigned long long* best = (unsigned long long*)(ws + WS_BEST);
  float* counts = (float*)(ws + WS_COUNTS);
  float* embsum = (float*)(ws + WS_EMBSUM);
  float* loss_s = (float*)(ws + WS_LOSS);
  float* nsum   = (float*)(ws + WS_NSUM);
  unsigned* enmax = (unsigned*)(ws + WS_ENMAX);
  float* newcs  = (float*)(ws + WS_NEWCS);
  float* enorm  = (float*)(ws + WS_ENORM);
  float* znorm  = (float*)(ws + WS_ZNORM);
  u16*   e16    = (u16*)(ws + WS_E16);

  hipMemsetAsync(ws + WS_BEST, 0xFF, 262144, stream);          // best keys = +inf
  hipMemsetAsync(ws + WS_ZERO0, 0, WS_ZEROLEN, stream);        // counts/embsum/loss/nsum/enmax
  vq_norms_v8<<<dim3(264), dim3(128), 0, stream>>>(z, E, znorm, enorm, e16, enmax);
  vq_dist_mfma4<<<dim3(1024), dim3(256), 0, stream>>>(z, E, e16, znorm, enorm, enmax, best);
  vq_scatter_v8<<<dim3(1024), dim3(256), 0, stream>>>(z, E, best, embsum, loss_s,
                                                      out + O_ZQ, out + O_IDX, counts);
  vq_newcs_v7<<<dim3(4), dim3(256), 0, stream>>>(ema_cs, counts, newcs, nsum, loss_s,
                                                 out + O_LOSS, out + O_NCS);
  vq_newemb_v7<<<dim3(K_), dim3(256), 0, stream>>>(ema_es, embsum, newcs, nsum,
                                                   out + O_EMB, out + O_NES);
}

// Round 5
// 275.984 us; speedup vs baseline: 1.5620x; 1.3503x over previous
//
#include <hip/hip_runtime.h>

#define D_  256
#define K_  1024
#define HW_ 1024      // 32*32
#define N_  32768     // 32*HW_

// workspace layout (bytes)
#define WS_BEST    0          // u64[32768]  (memset 0xFF)
#define WS_COUNTS  262144     // f32[1024]
#define WS_EMBSUM  266240     // f32[262144]
#define WS_LOSS    1314816    // f32
#define WS_NSUM    1314820    // f32
#define WS_ENMAX   1314824    // u32 (max ||e||^2 bits)
#define WS_ZERO0   262144     // zero range start
#define WS_ZEROLEN 1052684    // covers counts..enmax
#define WS_NEWCS   1314828    // f32[1024]
#define WS_ENORM   1318924    // f32[1024]
#define WS_ZNORM   1323020    // f32[32768]
#define WS_E16     1454096    // fp16(512*E)[1024*256] = 512 KiB (16B aligned)
#define WS_TOTAL   1978384

// output offsets (f32 elements): (z_q_st, loss, indices, new_emb, new_cs, new_es)
// NOTE: the O_ZQ region doubles as zT (f32 transpose of z, [n][d]) between the
// vq_zt and vq_scatter dispatches; scatter fully overwrites it afterwards.
#define O_ZQ   0
#define O_LOSS 8388608
#define O_IDX  8388609
#define O_EMB  8421377
#define O_NCS  8683521
#define O_NES  8684545

typedef unsigned short u16;
typedef _Float16 f16x8 __attribute__((ext_vector_type(8)));  // 8 f16 = 4 VGPRs
typedef float f32x4 __attribute__((ext_vector_type(4)));

// pack two f32 -> two f16 (HW v_cvt_f16_f32, rne)
__device__ __forceinline__ unsigned f16x2pack(float a, float b) {
  union { _Float16 h; unsigned short u; } ca, cb;
  ca.h = (_Float16)a; cb.h = (_Float16)b;
  return (unsigned)ca.u | ((unsigned)cb.u << 16);
}

// numpy pairwise_sum of 256 squares: two 128-halves, 8 accumulators,
// combine ((r0+r1)+(r2+r3))+((r4+r5)+(r6+r7)). __f*_rn blocks FMA contraction.
__device__ __forceinline__ float pw256_sq(const float* __restrict__ p, int stride) {
  float tot0 = 0.f, tot1 = 0.f;
#pragma unroll
  for (int h = 0; h < 2; ++h) {
    const float* q = p + h * 128 * stride;
    float r[8];
#pragma unroll
    for (int j = 0; j < 8; ++j) { float x = q[j * stride]; r[j] = __fmul_rn(x, x); }
    for (int i = 8; i < 128; i += 8)
#pragma unroll
      for (int j = 0; j < 8; ++j) {
        float x = q[(i + j) * stride];
        r[j] = __fadd_rn(r[j], __fmul_rn(x, x));
      }
    float s = __fadd_rn(__fadd_rn(__fadd_rn(r[0], r[1]), __fadd_rn(r[2], r[3])),
                        __fadd_rn(__fadd_rn(r[4], r[5]), __fadd_rn(r[6], r[7])));
    if (h == 0) tot0 = s; else tot1 = s;
  }
  return __fadd_rn(tot0, tot1);
}

// ---------------- ||z_n||^2, ||e_k||^2 (np order), en_max, E->fp16*512 ----------------
__global__ void vq_norms_v9(const float* __restrict__ z, const float* __restrict__ E,
                            float* __restrict__ znorm, float* __restrict__ enorm,
                            u16* __restrict__ E16, unsigned* __restrict__ enmax) {
  int t = blockIdx.x * 128 + threadIdx.x;        // 264 x 128 = 33792
  if (t < N_) {
    const float* p = z + (t >> 10) * (D_ * HW_) + (t & 1023);  // stride HW_ over d
    znorm[t] = pw256_sq(p, HW_);
  } else if (t < N_ + K_) {
    int k = t - N_;
    float v = pw256_sq(E + k * D_, 1);
    enorm[k] = v;
    atomicMax(enmax, __float_as_uint(v));        // v > 0 -> bit-monotone
  }
  // E -> fp16(512*e): exact pow2 scale keeps tiny e out of the subnormal range
  unsigned* E16w = (unsigned*)E16;
  int gsz = gridDim.x * 128;
  for (int wd = t; wd < (K_ * D_ / 2); wd += gsz) {
    float2 x = *(const float2*)(E + 2 * wd);
    E16w[wd] = f16x2pack(512.0f * x.x, 512.0f * x.y);
  }
}

// ---------------- z transpose: zT[n][d] = z[b][d][hw] (bit-exact f32 copy) ----------------
// 2048 blocks: b = bi>>6; 4 d-tiles x 16 hw-tiles of 64x64. Coalesced both ways.
__global__ void vq_zt(const float* __restrict__ z, float* __restrict__ zT) {
  __shared__ float tile[64][65];
  const int tid = threadIdx.x;
  const int bi = blockIdx.x;
  const int b = bi >> 6;
  const int d0 = ((bi >> 4) & 3) * 64;
  const int hw0 = (bi & 15) * 64;
  const float* zb = z + b * (D_ * HW_);
#pragma unroll
  for (int it = 0; it < 16; ++it) {
    int d_l = it * 4 + (tid >> 6), t_l = tid & 63;
    tile[d_l][t_l] = zb[(d0 + d_l) * HW_ + hw0 + t_l];
  }
  __syncthreads();
  float* o = zT + (b * HW_ + hw0) * D_ + d0;
#pragma unroll
  for (int it = 0; it < 16; ++it) {
    int t_l = it * 4 + (tid >> 6), d_l = tid & 63;
    o[t_l * D_ + d_l] = tile[d_l][t_l];
  }
}

// Exact reference-numerics distance for one (token, code): sequential fp32 FMA
// chain over d=0..255 (byte-identical order to the v9/reference path), then
// fl(fl(zn - 2a) + en). Inputs via float4 streams (zT row + E row) -> 4x fewer
// address-unit requests than the round-4 scalar gather (which was ~80% of the
// kernel: ~1.4M TA reqs/CU). Key=(score_bits<<32)|code -> device atomicMin.
__device__ __attribute__((noinline)) void exact_update(
    const float* __restrict__ zTb, const float* __restrict__ E,
    int t, int c, const float* __restrict__ zn_s, const float* __restrict__ en_s,
    unsigned long long* __restrict__ best) {
  const float* zp = zTb + t * D_;
  const float* ep = E + c * D_;
  float a = 0.f;
  for (int d0 = 0; d0 < 256; d0 += 8) {
    float4 z0 = *(const float4*)(zp + d0);
    float4 z1 = *(const float4*)(zp + d0 + 4);
    float4 e0 = *(const float4*)(ep + d0);
    float4 e1 = *(const float4*)(ep + d0 + 4);
    a = __fmaf_rn(z0.x, e0.x, a); a = __fmaf_rn(z0.y, e0.y, a);
    a = __fmaf_rn(z0.z, e0.z, a); a = __fmaf_rn(z0.w, e0.w, a);
    a = __fmaf_rn(z1.x, e1.x, a); a = __fmaf_rn(z1.y, e1.y, a);
    a = __fmaf_rn(z1.z, e1.z, a); a = __fmaf_rn(z1.w, e1.w, a);
  }
  float s = __fadd_rn(__fsub_rn(zn_s[t], __fmul_rn(2.0f, a)), en_s[c & 511]);
  // s ~ 200..330 > 0 -> float bits monotone
  unsigned long long key = ((unsigned long long)__float_as_uint(s) << 32) | (unsigned)c;
  atomicMin(&best[t], key);
}

// VALU-speed 16-lane min via DPP (quad_perm ^1, ^2, row_half_mirror, row_mirror)
template <int CTRL>
__device__ __forceinline__ float dppmin(float v) {
  int p = __builtin_amdgcn_update_dpp(0, __float_as_int(v), CTRL, 0xF, 0xF, true);
  return fminf(v, __int_as_float(p));
}

#define TCAP 288   // per-wave trigger-list capacity (expected ~50 used w/ fp16 margin)

// ---------------- MFMA distance + argmin with exact verification ----------------
// 1024 blocks x 256 thr. Block = 64 tokens x 512 codes (XCD-pair: halves are
// blockIdx b and b+8 -> same XCD L2). Wave owns 128 codes in 4 chunks of 32.
// fp16 MFMA (z as f16, E as f16*512) -> ph = en - 2*(A/512). fp16's 11-bit
// significand shrinks the rigorous two-sided margin 8x vs bf16:
//   M = 2^-8*sqrt(zn*en_max) + 5e-4
// (per-side |ph-(S-zn)| <= 2*2^-10*||z||*||e|| + flush/round slop; x2 two-sided
// + fl(S) slop). ~3 candidates/token -> tiny drain. Approx pass only GATES;
// exact fp32 chain (np order) decides -> indices bit-match the v9 baseline.
__global__ __launch_bounds__(256, 3) void vq_dist_mfma5(
    const float* __restrict__ z, const float* __restrict__ E,
    const u16* __restrict__ E16, const float* __restrict__ zT,
    const float* __restrict__ znorm, const float* __restrict__ enorm,
    const unsigned* __restrict__ enmax,
    unsigned long long* __restrict__ best_g) {
  __shared__ __align__(16) u16 zt[32 * 64 * 8];          // 32 KiB, [kb][tok][8d]
  __shared__ float en_s[512];                             // this half's norms
  __shared__ float zn_s[64];
  __shared__ float mg_s[64];
  __shared__ unsigned rmin_s[64];                         // bits of (min ph)+4.0
  __shared__ unsigned tcount[4];
  __shared__ unsigned tlist[4][TCAP];

  const int tid = threadIdx.x;
  const int b = blockIdx.x;
  const int tile = (b & 7) | ((b >> 4) << 3);  // 0..511 (token tile)
  const int half = (b >> 3) & 1;               // code half; pair = b, b+8
  const int bimg = tile >> 4;
  const int hw0 = (tile & 15) << 6;
  const float* zb = z + bimg * (D_ * HW_) + hw0;
  const float* zTb = zT + (bimg * HW_ + hw0) * D_;
  unsigned long long* best = best_g + bimg * HW_ + hw0;

  if (tid < 64) {
    float zn = znorm[bimg * HW_ + hw0 + tid];
    zn_s[tid] = zn;
    float em = __uint_as_float(*enmax);
    mg_s[tid] = 0.00390625f * sqrtf(zn * em) + 5e-4f;  // fp16 margin (proven safe)
    rmin_s[tid] = 0xFFFFFFFFu;   // own-wave chunk-min always lands before read
  }
  if (tid < 4) tcount[tid] = 0;
  for (int i = tid; i < 512; i += 256) en_s[i] = enorm[half * 512 + i];

  // stage z tile -> f16 LDS. thread: tok = tid&63, kb = (tid>>6)*8 + r.
  // global: 64 lanes read 64 consecutive floats per instr (256B coalesced).
  {
    const int tok = tid & 63;
    const int kbase = (tid >> 6) * 8;
    for (int r = 0; r < 8; ++r) {
      int kb = kbase + r;
      unsigned pk[4];
#pragma unroll
      for (int j = 0; j < 4; ++j) {
        float x0 = zb[(kb * 8 + 2 * j) * HW_ + tok];
        float x1 = zb[(kb * 8 + 2 * j + 1) * HW_ + tok];
        pk[j] = f16x2pack(x0, x1);
      }
      uint4 wv; wv.x = pk[0]; wv.y = pk[1]; wv.z = pk[2]; wv.w = pk[3];
      *(uint4*)(zt + kb * 512 + tok * 8) = wv;       // 16B, conflict-free
    }
  }
  __syncthreads();

  const int lane = tid & 63;
  const int w = tid >> 6;
  const int l15 = lane & 15, g = lane >> 4;
  // B-frag base: row = code (l15), k-slice col = g*8; chunk/n/kk add offsets
  const u16* Eb = E16 + (unsigned)(half * 512 + w * 128 + l15) * D_ + g * 8;

  f16x8 efA[2], efB[2];
#pragma unroll
  for (int n = 0; n < 2; ++n)
    efA[n] = *(const f16x8*)(Eb + n * 16 * D_);          // prime: s=0 (ch0,kk0)

  f32x4 acc[4][2];

// one MFMA step: S = step id, EFU = ef bank consumed, EFF = bank filled for SN.
// Pure loads/MFMA — no branches, no calls (round-3 lesson: calls in the loop
// poison regalloc; round-2: force-inline blew I$).
#define MSTEP(S, EFU, EFF, SN)                                                   \
  {                                                                              \
    const int kk_ = (S) & 7;                                                     \
    {                                                                            \
      const int cn_ = (SN) >> 3, kn_ = (SN) & 7;                                 \
      _Pragma("unroll")                                                          \
      for (int n = 0; n < 2; ++n)                                                \
        EFF[n] = *(const f16x8*)(Eb + (cn_ * 32 + n * 16) * D_ + kn_ * 32);      \
    }                                                                            \
    f16x8 zf_[4];                                                                \
    _Pragma("unroll")                                                            \
    for (int m = 0; m < 4; ++m)                                                  \
      zf_[m] = *(const f16x8*)(zt + (kk_ * 4 + g) * 512 + (m * 16 + l15) * 8);   \
    _Pragma("unroll")                                                            \
    for (int m = 0; m < 4; ++m)                                                  \
      _Pragma("unroll")                                                          \
      for (int n = 0; n < 2; ++n)                                                \
        acc[m][n] = __builtin_amdgcn_mfma_f32_16x16x32_f16(zf_[m], EFU[n],       \
                                                           acc[m][n], 0, 0, 0);  \
  }

  for (int s2 = 0; s2 < 32; s2 += 2) {
    if ((s2 & 7) == 0) {               // chunk start: zero accumulators
      f32x4 z4 = {0.f, 0.f, 0.f, 0.f};
#pragma unroll
      for (int m = 0; m < 4; ++m)
#pragma unroll
        for (int n = 0; n < 2; ++n) acc[m][n] = z4;
    }
    MSTEP(s2, efA, efB, s2 + 1)                       // even step: use A, fill B
    MSTEP(s2 + 1, efB, efA, (s2 + 2) & 31)            // odd: use B, fill A (tail
                                                      //  wrap value never used)
    if (((s2 + 1) & 7) == 7) {         // chunk end: epilogue
      const int ch = s2 >> 3;
      const int cb_l = w * 128 + ch * 32;        // local (within half)
      const int cb_f = half * 512 + cb_l;        // full code id
      // ph = en - 2*(A/512) = fma(-1/256, A, en).
      // D layout: col=lane&15 (code), row=g*4+r (token).
      float enc[2];
#pragma unroll
      for (int n = 0; n < 2; ++n) enc[n] = en_s[cb_l + n * 16 + l15];
#pragma unroll
      for (int m = 0; m < 4; ++m)
#pragma unroll
        for (int n = 0; n < 2; ++n)
#pragma unroll
          for (int r = 0; r < 4; ++r)
            acc[m][n][r] = __builtin_fmaf(-0.00390625f, acc[m][n][r], enc[n]);
      // per-token chunk-min: 1 fmin + 4 DPP-min (pure VALU), one LDS atomic
#pragma unroll
      for (int m = 0; m < 4; ++m)
#pragma unroll
        for (int r = 0; r < 4; ++r) {
          float v = fminf(acc[m][0][r], acc[m][1][r]);
          v = dppmin<0xB1>(v);     // ^1 (quad_perm 1,0,3,2)
          v = dppmin<0x4E>(v);     // ^2 (quad_perm 2,3,0,1)
          v = dppmin<0x141>(v);    // row_half_mirror
          v = dppmin<0x140>(v);    // row_mirror
          if (l15 == 0) atomicMin(&rmin_s[m * 16 + g * 4 + r], __float_as_uint(v + 4.0f));
        }
      // triggers: ph <= runmin + M (stale/larger runmin safe: more triggers).
      // Overflow entries are DROPPED but counted -> post-loop full re-verify.
#pragma unroll
      for (int m = 0; m < 4; ++m)
#pragma unroll
        for (int r = 0; r < 4; ++r) {
          int t = m * 16 + g * 4 + r;
          float thr = (__uint_as_float(rmin_s[t]) - 4.0f) + mg_s[t];
#pragma unroll
          for (int n = 0; n < 2; ++n) {
            if (acc[m][n][r] <= thr) {
              unsigned pos = atomicAdd(&tcount[w], 1u);
              if (pos < TCAP)
                tlist[w][pos] = ((unsigned)t << 16) | (unsigned)(cb_f + n * 16 + l15);
            }
          }
        }
    }
  }
#undef MSTEP

  // drain own wave's trigger list: exact recompute into global best
  {
    unsigned cnt = tcount[w];
    if (cnt <= TCAP) {
      for (unsigned basei = 0; basei < cnt; basei += 64) {
        unsigned i = basei + (unsigned)lane;
        if (i < cnt) {
          unsigned e = tlist[w][i];
          exact_update(zTb, E, (int)(e >> 16), (int)(e & 1023u), zn_s, en_s, best);
        }
      }
    } else {
      // overflow (astronomically rare): exactly verify this wave's whole tile
      const int c0 = half * 512 + w * 128;
      for (unsigned i = (unsigned)lane; i < 64u * 128u; i += 64) {
        exact_update(zTb, E, (int)(i >> 7), c0 + (int)(i & 127u), zn_s, en_s, best);
      }
    }
  }
}

// ---------------- z_q_st + loss + embed_sum + idx + counts (all f32) ----------------
__global__ __launch_bounds__(256, 1) void vq_scatter_v8(
    const float* __restrict__ z, const float* __restrict__ E,
    const unsigned long long* __restrict__ best, float* __restrict__ embsum,
    float* __restrict__ loss_sum, float* __restrict__ out_zq,
    float* __restrict__ out_idx, float* __restrict__ counts) {
  __shared__ float zt[256 * 33];     // staged z, overwritten in-place with z_q_st
  __shared__ int idx_s[32];
  __shared__ float wred[4];
  const int tid = threadIdx.x;
  const int tile = blockIdx.x;       // 0..1023
  const int b = tile >> 5;
  const int hw0 = (tile & 31) * 32;
  const float* zb = z + b * (D_ * HW_) + hw0;
  if (tid < 32) {
    int k = (int)(best[b * HW_ + hw0 + tid] & 1023ull);   // in-range by construction
    idx_s[tid] = k;
    out_idx[b * HW_ + hw0 + tid] = (float)k;
    atomicAdd(&counts[k], 1.0f);
  }
#pragma unroll
  for (int r = 0; r < 8; ++r) {
    int ii = r * 256 + tid;
    int d = ii >> 3, t4 = (ii & 7) * 4;
    float4 v = *(const float4*)(zb + d * HW_ + t4);
    float* p = zt + d * 33 + t4;
    p[0] = v.x; p[1] = v.y; p[2] = v.z; p[3] = v.w;
  }
  __syncthreads();

  const int w = tid >> 6, lane = tid & 63;
  float lsum = 0.f;
  for (int tt = 0; tt < 8; ++tt) {
    int t = w * 8 + tt;
    int k = idx_s[t];                      // wave-uniform
    const float* Er = E + k * D_;
    float* es = embsum + k * D_;
#pragma unroll
    for (int i = 0; i < 4; ++i) {
      int d = i * 64 + lane;
      float e = Er[d];
      float zv = zt[d * 33 + t];           // unique (t,d) owner -> safe in-place
      float df = __fsub_rn(zv, e);
      lsum += df * df;
      zt[d * 33 + t] = __fadd_rn(zv, __fsub_rn(e, zv));  // ref: z + (z_q - z)
      atomicAdd(es + d, zv);
    }
  }
#pragma unroll
  for (int o = 32; o > 0; o >>= 1) lsum += __shfl_down(lsum, o, 64);
  if (lane == 0) wred[w] = lsum;
  __syncthreads();
  if (tid == 0) atomicAdd(loss_sum, wred[0] + wred[1] + wred[2] + wred[3]);

  float* ob = out_zq + b * (D_ * HW_) + hw0;
#pragma unroll 4
  for (int r = 0; r < 32; ++r) {
    int d = r * 8 + (tid >> 5);
    int t = tid & 31;
    ob[d * HW_ + t] = zt[d * 33 + t];      // coalesced 128B-chunk f32 stores
  }
}

// ---------------- EMA cluster-size + n + loss finalize ----------------
__global__ void vq_newcs_v7(const float* __restrict__ cs_in, const float* __restrict__ counts,
                            float* __restrict__ newcs, float* __restrict__ nsum,
                            const float* __restrict__ loss_sum,
                            float* __restrict__ out_loss, float* __restrict__ out_ncs) {
  int k = blockIdx.x * 256 + threadIdx.x;
  float v = __fadd_rn(__fmul_rn(0.99f, cs_in[k]), __fmul_rn(0.01f, counts[k]));
  newcs[k] = v;
  out_ncs[k] = v;
  float s = v;
#pragma unroll
  for (int o = 32; o > 0; o >>= 1) s += __shfl_down(s, o, 64);
  __shared__ float w[4];
  if ((threadIdx.x & 63) == 0) w[threadIdx.x >> 6] = s;
  __syncthreads();
  if (threadIdx.x == 0) atomicAdd(nsum, w[0] + w[1] + w[2] + w[3]);
  if (k == 0) out_loss[0] = loss_sum[0] * (1.0f / 8388608.0f);
}

// ---------------- new_es + new_embedding ----------------
__global__ void vq_newemb_v7(const float* __restrict__ es_in, const float* __restrict__ embsum,
                             const float* __restrict__ newcs, const float* __restrict__ nsum,
                             float* __restrict__ out_emb, float* __restrict__ out_nes) {
  int k = blockIdx.x, d = threadIdx.x;
  float n = *nsum;
  float cs = (newcs[k] + 1e-5f) / (n + 1024.0f * 1e-5f) * n;   // ref formula order
  float es = __fadd_rn(__fmul_rn(0.99f, es_in[k * D_ + d]),
                       __fmul_rn(0.01f, embsum[k * D_ + d]));
  out_nes[k * D_ + d] = es;
  out_emb[k * D_ + d] = es / cs;
}

extern "C" void kernel_launch(void* const* d_in, const int* in_sizes, int n_in,
                              void* d_out, int out_size, void* d_ws, size_t ws_size,
                              hipStream_t stream) {
  (void)in_sizes; (void)n_in; (void)out_size; (void)ws_size;
  const float* z       = (const float*)d_in[0];
  const float* E       = (const float*)d_in[1];
  const float* ema_cs  = (const float*)d_in[2];
  const float* ema_es  = (const float*)d_in[3];
  float* out = (float*)d_out;
  char* ws = (char*)d_ws;
  unsigned long long* best = (unsigned long long*)(ws + WS_BEST);
  float* counts = (float*)(ws + WS_COUNTS);
  float* embsum = (float*)(ws + WS_EMBSUM);
  float* loss_s = (float*)(ws + WS_LOSS);
  float* nsum   = (float*)(ws + WS_NSUM);
  unsigned* enmax = (unsigned*)(ws + WS_ENMAX);
  float* newcs  = (float*)(ws + WS_NEWCS);
  float* enorm  = (float*)(ws + WS_ENORM);
  float* znorm  = (float*)(ws + WS_ZNORM);
  u16*   e16    = (u16*)(ws + WS_E16);
  float* zT     = out + O_ZQ;   // scratch: fully overwritten by vq_scatter later

  hipMemsetAsync(ws + WS_BEST, 0xFF, 262144, stream);          // best keys = +inf
  hipMemsetAsync(ws + WS_ZERO0, 0, WS_ZEROLEN, stream);        // counts/embsum/loss/nsum/enmax
  vq_norms_v9<<<dim3(264), dim3(128), 0, stream>>>(z, E, znorm, enorm, e16, enmax);
  vq_zt<<<dim3(2048), dim3(256), 0, stream>>>(z, zT);
  vq_dist_mfma5<<<dim3(1024), dim3(256), 0, stream>>>(z, E, e16, zT, znorm, enorm,
                                                      enmax, best);
  vq_scatter_v8<<<dim3(1024), dim3(256), 0, stream>>>(z, E, best, embsum, loss_s,
                                                      out + O_ZQ, out + O_IDX, counts);
  vq_newcs_v7<<<dim3(4), dim3(256), 0, stream>>>(ema_cs, counts, newcs, nsum, loss_s,
                                                 out + O_LOSS, out + O_NCS);
  vq_newemb_v7<<<dim3(K_), dim3(256), 0, stream>>>(ema_es, embsum, newcs, nsum,
                                                   out + O_EMB, out + O_NES);
}